// Round 10
// baseline (105.022 us; speedup 1.0000x reference)
//
#include <hip/hip_runtime.h>

// Problem constants (reference: B=1, T=2048, H=32, D=64, SCALE=1/64, DEG=2)
#define T_DIM 2048
#define H_DIM 32
#define D_DIM 64
#define SCALE_F 0.015625f
#define ROWSTRIDE 2048      // H_DIM * D_DIM floats per t-row

typedef unsigned short ushort;
typedef __attribute__((ext_vector_type(8))) short short8;   // 8 bf16
typedef __attribute__((ext_vector_type(16))) float f32x16;  // 32x32 MFMA acc
typedef __attribute__((ext_vector_type(2))) float f32x2;
typedef __attribute__((ext_vector_type(4))) float f32x4;

#define MFMA32(A, B, C) __builtin_amdgcn_mfma_f32_32x32x16_bf16((A), (B), (C), 0, 0, 0)

// ---------------------------------------------------------------------------
// Kernel 1: per-head inclusive cumsum of g over T -> gc stored [H][T]  (B=1)
// ---------------------------------------------------------------------------
__global__ __launch_bounds__(256)
void cumsum_g_kernel(const float* __restrict__ g, float* __restrict__ gc) {
    const int h = blockIdx.x;
    const int tid = threadIdx.x;
    const int PER = T_DIM / 256;        // 8

    __shared__ float sums[256];

    float loc[8];
    float run = 0.f;
    const int t0 = tid * PER;
    for (int i = 0; i < PER; ++i) {
        run += g[(size_t)(t0 + i) * H_DIM + h];
        loc[i] = run;
    }
    sums[tid] = run;
    __syncthreads();

    for (int off = 1; off < 256; off <<= 1) {
        float vv = (tid >= off) ? sums[tid - off] : 0.f;
        __syncthreads();
        sums[tid] += vv;
        __syncthreads();
    }
    float excl = (tid == 0) ? 0.f : sums[tid - 1];

    for (int i = 0; i < PER; ++i)
        gc[(size_t)h * T_DIM + t0 + i] = excl + loc[i];
}

// ---------------------------------------------------------------------------
// Helpers
// ---------------------------------------------------------------------------
__device__ __forceinline__ short8 ld8(const ushort* p) {
    return *reinterpret_cast<const short8*>(p);
}

__device__ __forceinline__ unsigned cvt_pk_bf16(float lo, float hi) {
    unsigned r;
    asm("v_cvt_pk_bf16_f32 %0, %1, %2" : "=v"(r) : "v"(lo), "v"(hi));
    return r;
}

// Pack 8 f32 W-values (4 f32x2 pairs, C-layout half) into the PV A-operand
// fragment via cvt_pk + permlane32_swap. (Layout verified R3-R9.)
__device__ __forceinline__ short8 pack_w2(const f32x2* w2) {
    unsigned p0 = cvt_pk_bf16(w2[0][0], w2[0][1]);
    unsigned p1 = cvt_pk_bf16(w2[1][0], w2[1][1]);
    unsigned p2 = cvt_pk_bf16(w2[2][0], w2[2][1]);
    unsigned p3 = cvt_pk_bf16(w2[3][0], w2[3][1]);
    asm("v_permlane32_swap_b32 %0, %1" : "+v"(p0), "+v"(p2));
    asm("v_permlane32_swap_b32 %0, %1" : "+v"(p1), "+v"(p3));
    union { unsigned u[4]; short8 s; } af;
    af.u[0] = p0; af.u[1] = p1; af.u[2] = p2; af.u[3] = p3;
    return af.s;
}

// One 32s x 32q unit from LDS frag tiles (XOR-swizzled layout).
// MODE 0: full, 1: diag (s<=l31). Read offsets precomputed (loK/loV).
template<int MODE>
__device__ __forceinline__ void unit32(
    const ushort* ldsK, const ushort* ldsV,
    const int (&loK)[4], const int (&loV)[4],
    int hi, int l31,
    const short8 (&qr)[4], f32x16& o0, f32x16& o1, f32x2& den2)
{
    const short8 kf0 = ld8(ldsK + loK[0]);
    const short8 kf1 = ld8(ldsK + loK[1]);
    const short8 kf2 = ld8(ldsK + loK[2]);
    const short8 kf3 = ld8(ldsK + loK[3]);
    const short8 vf0 = ld8(ldsV + loV[0]);   // dblk0 kh2=0
    const short8 vf1 = ld8(ldsV + loV[1]);   // dblk0 kh2=1
    const short8 vf2 = ld8(ldsV + loV[2]);   // dblk1 kh2=0
    const short8 vf3 = ld8(ldsV + loV[3]);   // dblk1 kh2=1

    f32x16 c;
#pragma unroll
    for (int i = 0; i < 16; ++i) c[i] = 0.f;
    c = MFMA32(kf0, qr[0], c);
    c = MFMA32(kf1, qr[1], c);
    c = MFMA32(kf2, qr[2], c);
    c = MFMA32(kf3, qr[3], c);

    f32x2 w2[8];
#pragma unroll
    for (int i = 0; i < 8; ++i) {
        const int r0 = 2 * i;
        f32x2 x; x[0] = c[r0]; x[1] = c[r0 + 1];
        f32x2 ww = x * x;
        if (MODE == 1) {
            const int sl0 = (r0 & 3) + 8 * (r0 >> 2) + 4 * hi;
            ww[0] = (sl0 <= l31) ? ww[0] : 0.f;
            ww[1] = (sl0 + 1 <= l31) ? ww[1] : 0.f;
        }
        w2[i] = ww;
        den2 += ww;
    }
    const short8 a0 = pack_w2(&w2[0]);     // kh2 = 0
    o0 = MFMA32(a0, vf0, o0);
    o1 = MFMA32(a0, vf2, o1);
    const short8 a1 = pack_w2(&w2[4]);     // kh2 = 1
    o0 = MFMA32(a1, vf1, o0);
    o1 = MFMA32(a1, vf3, o1);
}

// ---------------------------------------------------------------------------
// Fused staging: fp32 global -> decay-scaled bf16 frag layout in LDS, with
// XOR-swizzled chunk addresses (conflict-free ds_write_b128).
// Period = 128 s-rows. 512 threads x 2 slots for K and V each.
//   K chunk16 = (r>>5)*256 + ks*64 + hh*32 + ((r&31) ^ (2ks+hh))
//   V chunk16 = tile*256 + c3*32 + (l31 ^ c3),  c3 = dblk*4+kh2*2+hiv
// ---------------------------------------------------------------------------
struct KS { f32x4 a, b; float g; };
struct VS { float v0, v1, v2, v3, v4, v5, v6, v7; };

__device__ __forceinline__ void issue_k(KS& s, const float* kg,
                                        const float* gch, int s0, int slot) {
    const int r  = slot >> 3;           // 0..127
    const int d0 = (slot & 7) * 8;
    const float* p = kg + (size_t)(s0 + r) * ROWSTRIDE + d0;
    s.a = *reinterpret_cast<const f32x4*>(p);
    s.b = *reinterpret_cast<const f32x4*>(p + 4);
    s.g = gch[s0 + r];
}

__device__ __forceinline__ void write_k(const KS& s, ushort* bufK, int slot) {
    const int r  = slot >> 3;
    const int ks = (slot & 7) >> 1;
    const int hh = slot & 1;
    const float ek = __expf(-0.5f * s.g);
    union { unsigned u[4]; short8 s8; } o;
    o.u[0] = cvt_pk_bf16(s.a[0] * ek, s.a[1] * ek);
    o.u[1] = cvt_pk_bf16(s.a[2] * ek, s.a[3] * ek);
    o.u[2] = cvt_pk_bf16(s.b[0] * ek, s.b[1] * ek);
    o.u[3] = cvt_pk_bf16(s.b[2] * ek, s.b[3] * ek);
    const int chunk = (r >> 5) * 256 + ks * 64 + hh * 32
                    + ((r & 31) ^ (2 * ks + hh));
    *reinterpret_cast<short8*>(bufK + chunk * 8) = o.s8;
}

__device__ __forceinline__ void issue_v(VS& s, const float* vg, int s0, int slot) {
    const int c = slot >> 5;            // 0..31
    const int l31 = slot & 31;
    const int tile = c >> 3, c3 = c & 7;
    const int dblk = c3 >> 2, kh2 = (c3 >> 1) & 1, hiv = c3 & 1;
    const int tb = s0 + tile * 32 + kh2 * 16 + hiv * 8;
    const float* p = vg + (size_t)tb * ROWSTRIDE + dblk * 32 + l31;
    s.v0 = p[0 * ROWSTRIDE]; s.v1 = p[1 * ROWSTRIDE];
    s.v2 = p[2 * ROWSTRIDE]; s.v3 = p[3 * ROWSTRIDE];
    s.v4 = p[4 * ROWSTRIDE]; s.v5 = p[5 * ROWSTRIDE];
    s.v6 = p[6 * ROWSTRIDE]; s.v7 = p[7 * ROWSTRIDE];
}

__device__ __forceinline__ void write_v(const VS& s, ushort* bufV, int slot) {
    const int c = slot >> 5, l31 = slot & 31;
    const int tile = c >> 3, c3 = c & 7;
    union { unsigned u[4]; short8 s8; } o;
    o.u[0] = cvt_pk_bf16(s.v0, s.v1);
    o.u[1] = cvt_pk_bf16(s.v2, s.v3);
    o.u[2] = cvt_pk_bf16(s.v4, s.v5);
    o.u[3] = cvt_pk_bf16(s.v6, s.v7);
    const int chunk = tile * 256 + c3 * 32 + (l31 ^ c3);
    *reinterpret_cast<short8*>(bufV + chunk * 8) = o.s8;
}

// ---------------------------------------------------------------------------
// Kernel 2: fused retention. Grid 512 = 16 ranks x 32 heads; QB = 15-rank
// (LPT). 512 threads, 8 waves: qi = w&3 (32-row q-sub), si = w>>2.
// Period = 128 s-rows (4 subtiles); wave handles subtiles 4J+2si, 4J+2si+1
// -> 2 independent unit chains per period, one barrier per period.
// ---------------------------------------------------------------------------
__global__ __launch_bounds__(512, 4)
void retention_fused_kernel(const float* __restrict__ q,
                            const float* __restrict__ k,
                            const float* __restrict__ v,
                            const float* __restrict__ gc,
                            float* __restrict__ out) {
    __shared__ ushort buf[2][16384];    // [cur][K:8192 | V:8192] = 2 x 32KB

    const int bid = blockIdx.x;
    const int h   = bid & 31;           // h%8 == bid%8 -> head-home XCD
    const int QB  = 15 - (bid >> 5);    // longest first (LPT)

    const int tid = threadIdx.x;
    const int w   = tid >> 6;
    const int qi  = w & 3;
    const int si  = w >> 2;
    const int lane = tid & 63;
    const int hi  = lane >> 5;
    const int l31 = lane & 31;
    const int myT32 = 4 * QB + qi;

    // swizzled read offsets (loop-invariant)
    int loK[4], loV[4];
#pragma unroll
    for (int ks = 0; ks < 4; ++ks)
        loK[ks] = (ks * 64 + hi * 32 + (l31 ^ (2 * ks + hi))) * 8;
#pragma unroll
    for (int m = 0; m < 4; ++m) {
        const int c3 = (m >> 1) * 4 + (m & 1) * 2 + hi;
        loV[m] = (c3 * 32 + (l31 ^ c3)) * 8;
    }

    const float* gch = gc + (size_t)h * T_DIM;
    const float* kg  = k + h * 64;
    const float* vg  = v + h * 64;

    // ---- Q frags from global (once): q̂ = q * SCALE * exp(gc_t/2) ----
    short8 qr[4];
    {
        const int t = myT32 * 32 + l31;
        const float eq = SCALE_F * __expf(0.5f * gch[t]);
        const float* qrow = q + (size_t)t * ROWSTRIDE + h * 64 + hi * 8;
#pragma unroll
        for (int ks = 0; ks < 4; ++ks) {
            f32x4 fa = *reinterpret_cast<const f32x4*>(qrow + ks * 16);
            f32x4 fb = *reinterpret_cast<const f32x4*>(qrow + ks * 16 + 4);
            union { unsigned u[4]; short8 s8; } o;
            o.u[0] = cvt_pk_bf16(fa[0] * eq, fa[1] * eq);
            o.u[1] = cvt_pk_bf16(fa[2] * eq, fa[3] * eq);
            o.u[2] = cvt_pk_bf16(fb[0] * eq, fb[1] * eq);
            o.u[3] = cvt_pk_bf16(fb[2] * eq, fb[3] * eq);
            qr[ks] = o.s8;
        }
    }

    f32x16 o0, o1;
#pragma unroll
    for (int i = 0; i < 16; ++i) { o0[i] = 0.f; o1[i] = 0.f; }
    f32x2 d2; d2[0] = 0.f; d2[1] = 0.f;

    const int NJ = QB + 1;              // 128-s periods

    // prologue: stage period 0 (two slots per thread for K and V)
    KS k0s, k1s; VS v0s, v1s;
    issue_k(k0s, kg, gch, 0, tid);
    issue_k(k1s, kg, gch, 0, tid + 512);
    issue_v(v0s, vg, 0, tid);
    issue_v(v1s, vg, 0, tid + 512);
    write_k(k0s, buf[0], tid);
    write_k(k1s, buf[0], tid + 512);
    write_v(v0s, buf[0] + 8192, tid);
    write_v(v1s, buf[0] + 8192, tid + 512);
    __syncthreads();

    for (int J = 0; J < NJ; ++J) {
        const int cur = J & 1;
        if (J + 1 < NJ) {               // issue next period's loads early
            const int s0n = (J + 1) * 128;
            issue_k(k0s, kg, gch, s0n, tid);
            issue_k(k1s, kg, gch, s0n, tid + 512);
            issue_v(v0s, vg, s0n, tid);
            issue_v(v1s, vg, s0n, tid + 512);
        }
        const ushort* bK = buf[cur];
        const ushort* bV = buf[cur] + 8192;
        const int c1 = 4 * J + 2 * si;
        const int sub1 = 2 * si, sub2 = 2 * si + 1;

        if (c1 < myT32)
            unit32<0>(bK + sub1 * 2048, bV + sub1 * 2048, loK, loV, hi, l31, qr, o0, o1, d2);
        else if (c1 == myT32)
            unit32<1>(bK + sub1 * 2048, bV + sub1 * 2048, loK, loV, hi, l31, qr, o0, o1, d2);

        if (c1 + 1 < myT32)
            unit32<0>(bK + sub2 * 2048, bV + sub2 * 2048, loK, loV, hi, l31, qr, o0, o1, d2);
        else if (c1 + 1 == myT32)
            unit32<1>(bK + sub2 * 2048, bV + sub2 * 2048, loK, loV, hi, l31, qr, o0, o1, d2);

        if (J + 1 < NJ) {               // write after compute (latency hidden)
            write_k(k0s, buf[cur ^ 1], tid);
            write_k(k1s, buf[cur ^ 1], tid + 512);
            write_v(v0s, buf[cur ^ 1] + 8192, tid);
            write_v(v1s, buf[cur ^ 1] + 8192, tid + 512);
        }
        __syncthreads();                // writes visible; reads of cur done
    }

    // ---- epilogue: merge si-partials in (now free) staging LDS ----
    float* pm  = (float*)&buf[0][0];    // 32KB: [qi][row32][col64]
    float* pmd = (float*)&buf[1][0];    // den: [qi*2+si][32]

    float den = d2[0] + d2[1];
    den += __shfl_xor(den, 32);
    if (hi == 0) pmd[(qi * 2 + si) * 32 + l31] = den;

    if (si == 0) {
#pragma unroll
        for (int rr = 0; rr < 16; ++rr) {
            const int row = (rr & 3) + 8 * (rr >> 2) + 4 * hi;
            pm[(qi * 32 + row) * 64 + l31]      = o0[rr];
            pm[(qi * 32 + row) * 64 + 32 + l31] = o1[rr];
        }
    }
    __syncthreads();
    if (si == 1) {
#pragma unroll
        for (int rr = 0; rr < 16; ++rr) {
            const int row = (rr & 3) + 8 * (rr >> 2) + 4 * hi;
            pm[(qi * 32 + row) * 64 + l31]      += o0[rr];
            pm[(qi * 32 + row) * 64 + 32 + l31] += o1[rr];
        }
    }
    __syncthreads();

    // final write: 512 threads -> 128 rows x 64 cols
    {
        const int row  = tid >> 2;          // 0..127
        const int qq   = row >> 5;
        const int r32  = row & 31;
        const int dseg = (tid & 3) * 16;
        const float dtot = pmd[(qq * 2 + 0) * 32 + r32]
                         + pmd[(qq * 2 + 1) * 32 + r32];
        const float inv = 1.f / fmaxf(dtot, 1.f);
        const float* src = pm + (qq * 32 + r32) * 64 + dseg;
        float* dst = out + ((size_t)(QB * 128 + row) * H_DIM + h) * 64 + dseg;
#pragma unroll
        for (int jv = 0; jv < 4; ++jv) {
            f32x4 s = *reinterpret_cast<const f32x4*>(src + 4 * jv);
            s *= inv;
            *reinterpret_cast<f32x4*>(dst + 4 * jv) = s;
        }
    }
}

// ---------------------------------------------------------------------------
extern "C" void kernel_launch(void* const* d_in, const int* in_sizes, int n_in,
                              void* d_out, int out_size, void* d_ws, size_t ws_size,
                              hipStream_t stream) {
    const float* q = (const float*)d_in[0];
    const float* k = (const float*)d_in[1];
    const float* v = (const float*)d_in[2];
    const float* g = (const float*)d_in[3];
    float* out = (float*)d_out;

    float* gc = (float*)d_ws;   // H*T floats = 256 KB

    cumsum_g_kernel<<<H_DIM, 256, 0, stream>>>(g, gc);
    retention_fused_kernel<<<512, 512, 0, stream>>>(q, k, v, gc, out);
}

// Round 11
// 52.482 us; speedup vs baseline: 2.0011x; 2.0011x over previous
//
#include <hip/hip_runtime.h>

// Problem constants (reference: B=1, T=2048, H=32, D=64, SCALE=1/64, DEG=2)
#define T_DIM 2048
#define H_DIM 32
#define D_DIM 64
#define SCALE_F 0.015625f
#define TILE_STRIDE 2048    // ushorts per (h, 32-row frag tile) = 4KB

typedef unsigned short ushort;
typedef __attribute__((ext_vector_type(8))) short short8;   // 8 bf16
typedef __attribute__((ext_vector_type(16))) float f32x16;  // 32x32 MFMA acc
typedef __attribute__((ext_vector_type(2))) float f32x2;
typedef __attribute__((ext_vector_type(4))) float f32x4;

#define MFMA32(A, B, C) __builtin_amdgcn_mfma_f32_32x32x16_bf16((A), (B), (C), 0, 0, 0)

// ---------------------------------------------------------------------------
// Kernel 1: per-head inclusive cumsum of g over T -> gc stored [H][T]  (B=1)
// ---------------------------------------------------------------------------
__global__ __launch_bounds__(256)
void cumsum_g_kernel(const float* __restrict__ g, float* __restrict__ gc) {
    const int h = blockIdx.x;
    const int tid = threadIdx.x;
    const int PER = T_DIM / 256;        // 8

    __shared__ float sums[256];

    float loc[8];
    float run = 0.f;
    const int t0 = tid * PER;
    for (int i = 0; i < PER; ++i) {
        run += g[(size_t)(t0 + i) * H_DIM + h];
        loc[i] = run;
    }
    sums[tid] = run;
    __syncthreads();

    for (int off = 1; off < 256; off <<= 1) {
        float vv = (tid >= off) ? sums[tid - off] : 0.f;
        __syncthreads();
        sums[tid] += vv;
        __syncthreads();
    }
    float excl = (tid == 0) ? 0.f : sums[tid - 1];

    for (int i = 0; i < PER; ++i)
        gc[(size_t)h * T_DIM + t0 + i] = excl + loc[i];
}

// ---------------------------------------------------------------------------
__device__ __forceinline__ ushort f2bf(float x) {
    unsigned u = __float_as_uint(x);
    unsigned r = (u + 0x7fffu + ((u >> 16) & 1u)) >> 16;
    return (ushort)r;
}

// ---------------------------------------------------------------------------
// Prep: frag-major bf16 buffers so ALL main-loop frag loads coalesce.
//   qfrag/kfrag: [h][t32][ks(4)][hi(2)][l31(32)][8]  content q̂/k̂[32*t32+l31][16ks+8hi+j]
//   vfrag:       [h][s32][dblk(2)][kh2(2)][hi(2)][l31(32)][8]
//                 content v̂[32*s32+16kh2+8hi+j][32dblk+l31]
// q̂ = q*SCALE*exp(gc/2), k̂ = k*exp(-gc/2), v̂ = bf16(v).  (Verified R5.)
// ---------------------------------------------------------------------------
__global__ __launch_bounds__(256)
void prep_kernel(const float* __restrict__ q, const float* __restrict__ k,
                 const float* __restrict__ v, const float* __restrict__ gc,
                 ushort* __restrict__ qfrag, ushort* __restrict__ kfrag,
                 ushort* __restrict__ vfrag) {
    __shared__ ushort qt_l[64 * 64];   // swizzled [row][slot] 16B chunks
    __shared__ ushort kt_l[64 * 64];

    const int h   = blockIdx.x;
    const int tt  = blockIdx.y;        // 64-row chunk
    const int tid = threadIdx.x;

    // ---- stage q̂,k̂ rows into swizzled LDS (coalesced f32 reads) ----
    {
        const int r    = tid >> 2;          // 0..63
        const int dseg = (tid & 3) * 16;    // 16 floats
        const int t    = tt * 64 + r;
        const float gct = gc[(size_t)h * T_DIM + t];
        const float eq = SCALE_F * __expf(0.5f * gct);
        const float ek = __expf(-0.5f * gct);
        const float* qp = q + ((size_t)t * H_DIM + h) * 64 + dseg;
        const float* kp = k + ((size_t)t * H_DIM + h) * 64 + dseg;
        union { ushort u[16]; uint4 uu[2]; } oq, ok;
#pragma unroll
        for (int i = 0; i < 16; ++i) {
            oq.u[i] = f2bf(qp[i] * eq);
            ok.u[i] = f2bf(kp[i] * ek);
        }
        const int c0 = (tid & 3) * 2;       // 16B chunk index base
#pragma unroll
        for (int cc = 0; cc < 2; ++cc) {
            const int slot = (c0 + cc) ^ (r & 7);
            *reinterpret_cast<uint4*>(&qt_l[r * 64 + slot * 8]) = oq.uu[cc];
            *reinterpret_cast<uint4*>(&kt_l[r * 64 + slot * 8]) = ok.uu[cc];
        }
    }
    __syncthreads();

    // ---- q/k frag writes: 512 16B-chunks each, coalesced stores ----
#pragma unroll
    for (int n = 0; n < 2; ++n) {
        const int ch   = tid + 256 * n;     // 0..511
        const int l31  = ch & 31;
        const int hi   = (ch >> 5) & 1;
        const int ks   = (ch >> 6) & 3;
        const int t32r = ch >> 8;           // 0/1
        const int row  = t32r * 32 + l31;
        const int slot = (2 * ks + hi) ^ (row & 7);
        uint4 qq = *reinterpret_cast<const uint4*>(&qt_l[row * 64 + slot * 8]);
        uint4 kk = *reinterpret_cast<const uint4*>(&kt_l[row * 64 + slot * 8]);
        const size_t base = ((size_t)h * 64 + tt * 2 + t32r) * TILE_STRIDE
                          + (size_t)(((ks * 2 + hi) * 32) + l31) * 8;
        *reinterpret_cast<uint4*>(qfrag + base) = qq;
        *reinterpret_cast<uint4*>(kfrag + base) = kk;
    }

    // ---- v frags: direct global gather (all loads/stores coalesced) ----
#pragma unroll
    for (int n = 0; n < 2; ++n) {
        const int c9   = (tid >> 5) + 8 * n;  // 0..15
        const int l31  = tid & 31;
        const int hi   = c9 & 1;
        const int kh2  = (c9 >> 1) & 1;
        const int dblk = (c9 >> 2) & 1;
        const int s32r = c9 >> 3;
        const int tb = tt * 64 + s32r * 32 + kh2 * 16 + hi * 8;
        union { ushort u[8]; uint4 uu; } ov;
#pragma unroll
        for (int j = 0; j < 8; ++j)
            ov.u[j] = f2bf(v[((size_t)(tb + j) * H_DIM + h) * 64 + dblk * 32 + l31]);
        const size_t base = ((size_t)h * 64 + tt * 2 + s32r) * TILE_STRIDE
                          + (size_t)((((dblk * 2 + kh2) * 2 + hi) * 32) + l31) * 8;
        *reinterpret_cast<uint4*>(vfrag + base) = ov.uu;
    }
}

// ---------------------------------------------------------------------------
// Main kernel helpers
// ---------------------------------------------------------------------------
__device__ __forceinline__ short8 ld8(const ushort* p) {
    return *reinterpret_cast<const short8*>(p);
}

__device__ __forceinline__ unsigned cvt_pk_bf16(float lo, float hi) {
    unsigned r;
    asm("v_cvt_pk_bf16_f32 %0, %1, %2" : "=v"(r) : "v"(lo), "v"(hi));
    return r;
}

// Pack 8 f32 W-values (4 f32x2 pairs, C-layout half) into the PV A-operand
// fragment via cvt_pk + permlane32_swap. (Layout verified R3-R10.)
__device__ __forceinline__ short8 pack_w2(const f32x2* w2) {
    unsigned p0 = cvt_pk_bf16(w2[0][0], w2[0][1]);
    unsigned p1 = cvt_pk_bf16(w2[1][0], w2[1][1]);
    unsigned p2 = cvt_pk_bf16(w2[2][0], w2[2][1]);
    unsigned p3 = cvt_pk_bf16(w2[3][0], w2[3][1]);
    asm("v_permlane32_swap_b32 %0, %1" : "+v"(p0), "+v"(p2));
    asm("v_permlane32_swap_b32 %0, %1" : "+v"(p1), "+v"(p3));
    union { unsigned u[4]; short8 s; } af;
    af.u[0] = p0; af.u[1] = p1; af.u[2] = p2; af.u[3] = p3;
    return af.s;
}

// One 32s x 32q unit, frags loaded directly from global (L2-resident,
// single coalesced dwordx4 each). MODE 0: full, 1: diag (s_local <= l31).
template<int MODE>
__device__ __forceinline__ void unitD(
    const ushort* __restrict__ kb, const ushort* __restrict__ vb,
    int lofs, int hi, int l31,
    const short8 (&qr)[4], f32x16& o0, f32x16& o1, f32x2& den2)
{
    const short8 kf0 = ld8(kb + lofs);
    const short8 kf1 = ld8(kb + 512 + lofs);
    const short8 kf2 = ld8(kb + 1024 + lofs);
    const short8 kf3 = ld8(kb + 1536 + lofs);
    const short8 vf0 = ld8(vb + lofs);           // dblk0 kh2=0
    const short8 vf1 = ld8(vb + 512 + lofs);     // dblk0 kh2=1
    const short8 vf2 = ld8(vb + 1024 + lofs);    // dblk1 kh2=0
    const short8 vf3 = ld8(vb + 1536 + lofs);    // dblk1 kh2=1

    f32x16 c;
#pragma unroll
    for (int i = 0; i < 16; ++i) c[i] = 0.f;
    c = MFMA32(kf0, qr[0], c);
    c = MFMA32(kf1, qr[1], c);
    c = MFMA32(kf2, qr[2], c);
    c = MFMA32(kf3, qr[3], c);

    f32x2 w2[8];
#pragma unroll
    for (int i = 0; i < 8; ++i) {
        const int r0 = 2 * i;
        f32x2 x; x[0] = c[r0]; x[1] = c[r0 + 1];
        f32x2 ww = x * x;
        if (MODE == 1) {
            const int sl0 = (r0 & 3) + 8 * (r0 >> 2) + 4 * hi;
            ww[0] = (sl0 <= l31) ? ww[0] : 0.f;
            ww[1] = (sl0 + 1 <= l31) ? ww[1] : 0.f;
        }
        w2[i] = ww;
        den2 += ww;
    }
    const short8 a0 = pack_w2(&w2[0]);     // kh2 = 0
    o0 = MFMA32(a0, vf0, o0);
    o1 = MFMA32(a0, vf2, o1);
    const short8 a1 = pack_w2(&w2[4]);     // kh2 = 1
    o0 = MFMA32(a1, vf1, o0);
    o1 = MFMA32(a1, vf3, o1);
}

// ---------------------------------------------------------------------------
// Kernel 3: no-barrier split-K main. Grid 1024 = 32 pairs x 32 heads, ALL
// blocks co-resident (4/CU -> 16 waves/CU = 4/SIMD). 4 independent waves:
//   w0: (m=63-pair, even s)  w1: (63-pair, odd s)
//   w2: (m=pair,    even s)  w3: (pair,    odd s)
// Uniform 65 units/block, zero tail, no loop barriers. One end-merge in LDS.
// ---------------------------------------------------------------------------
__global__ __launch_bounds__(256, 4)
void retention_main_kernel(const ushort* __restrict__ qfrag,
                           const ushort* __restrict__ kfrag,
                           const ushort* __restrict__ vfrag,
                           float* __restrict__ out) {
    __shared__ float lds_o[2][32][64];   // 16 KB odd-wave partials
    __shared__ float lds_d[2][32];

    const int bid  = blockIdx.x;
    const int h    = bid & 31;           // h%8 == bid%8 -> head-home XCD
    const int pair = bid >> 5;           // 0..31
    const int tid  = threadIdx.x;
    const int w    = tid >> 6;
    const int lane = tid & 63;
    const int hi   = lane >> 5;
    const int l31  = lane & 31;
    const int lofs = hi * 256 + l31 * 8;

    const int m   = (w < 2) ? (63 - pair) : pair;   // 32-row q-subtile
    const int par = w & 1;                          // s-parity

    // Q frags (16 VGPR)
    short8 qr[4];
    {
        const ushort* qb = qfrag + ((size_t)h * 64 + m) * TILE_STRIDE;
#pragma unroll
        for (int ks = 0; ks < 4; ++ks) qr[ks] = ld8(qb + ks * 512 + lofs);
    }

    f32x16 o0, o1;
#pragma unroll
    for (int i = 0; i < 16; ++i) { o0[i] = 0.f; o1[i] = 0.f; }
    f32x2 d2; d2[0] = 0.f; d2[1] = 0.f;

    const ushort* khb = kfrag + (size_t)h * 64 * TILE_STRIDE;
    const ushort* vhb = vfrag + (size_t)h * 64 * TILE_STRIDE;

    int st = par;
    for (; st < m; st += 2)
        unitD<0>(khb + (size_t)st * TILE_STRIDE, vhb + (size_t)st * TILE_STRIDE,
                 lofs, hi, l31, qr, o0, o1, d2);
    if (st == m)   // diagonal unit belongs to the parity that matches m
        unitD<1>(khb + (size_t)m * TILE_STRIDE, vhb + (size_t)m * TILE_STRIDE,
                 lofs, hi, l31, qr, o0, o1, d2);

    float den = d2[0] + d2[1];
    den += __shfl_xor(den, 32);          // den for q-row l31 (both hi halves)

    const int slot = w >> 1;             // {w0,w1}->0 (63-pair), {w2,w3}->1 (pair)
    if (par == 1) {                      // odd waves stash partials
#pragma unroll
        for (int rr = 0; rr < 16; ++rr) {
            const int row = (rr & 3) + 8 * (rr >> 2) + 4 * hi;
            lds_o[slot][row][l31]      = o0[rr];
            lds_o[slot][row][32 + l31] = o1[rr];
        }
        if (hi == 0) lds_d[slot][l31] = den;
    }
    __syncthreads();
    if (par == 0) {                      // even waves merge + write out
        const float dtot = den + lds_d[slot][l31];
#pragma unroll
        for (int rr = 0; rr < 16; ++rr) {
            const int row = (rr & 3) + 8 * (rr >> 2) + 4 * hi;
            const float s0 = o0[rr] + lds_o[slot][row][l31];
            const float s1 = o1[rr] + lds_o[slot][row][32 + l31];
            const float dt = __shfl(dtot, row);
            const float inv = 1.f / fmaxf(dt, 1.f);
            const int t = m * 32 + row;
            float* op = out + ((size_t)t * H_DIM + h) * 64;
            op[l31]      = s0 * inv;
            op[32 + l31] = s1 * inv;
        }
    }
}

// ---------------------------------------------------------------------------
extern "C" void kernel_launch(void* const* d_in, const int* in_sizes, int n_in,
                              void* d_out, int out_size, void* d_ws, size_t ws_size,
                              hipStream_t stream) {
    const float* q = (const float*)d_in[0];
    const float* k = (const float*)d_in[1];
    const float* v = (const float*)d_in[2];
    const float* g = (const float*)d_in[3];
    float* out = (float*)d_out;

    const size_t GC_BYTES = (size_t)H_DIM * T_DIM * sizeof(float);   // 256 KB
    const size_t BF_ELEMS = (size_t)H_DIM * T_DIM * D_DIM;           // 4.2M ushorts

    float* gc = (float*)d_ws;
    ushort* qfrag = (ushort*)((char*)d_ws + GC_BYTES);
    ushort* kfrag = qfrag + BF_ELEMS;
    ushort* vfrag = kfrag + BF_ELEMS;

    cumsum_g_kernel<<<H_DIM, 256, 0, stream>>>(g, gc);
    prep_kernel<<<dim3(H_DIM, T_DIM / 64), 256, 0, stream>>>(q, k, v, gc,
                                                             qfrag, kfrag, vfrag);
    retention_main_kernel<<<1024, 256, 0, stream>>>(qfrag, kfrag, vfrag, out);
}